// Round 9
// baseline (386.706 us; speedup 1.0000x reference)
//
#include <hip/hip_runtime.h>

// AdaptiveGraph on MI355X — v9: decouple the 256MB A-write stream from the barrier'd MFMA loop.
// Evidence: R4 k_main wrote 279MB at 1.73TB/s (27% of the 6.5TB/s the poison fill proves) —
// store bursts between barriers never fill the write pipe. Split:
//  k_sv : rowsum + U (=out unnormalized; rsinv factors out of the row) fused in one barrier'd
//         pass: 128r blocks, staged ZC (coalesced), dbuf PT, 1 barrier/iter, scattered Bz
//         (4 MFMA per load), 70KB LDS -> 2 blocks/CU, grid 512. rowsum+Uacc atomics.
//  k_a  : ZERO-LDS ZERO-BARRIER A-writer (R2-proven indexing): scattered Af from L2 Zb,
//         reg Bfr, relu*rsinv, back-to-back nt float4 stores. grid 2048.
//  k_out: out = Uacc * rsinv (8MB).
// ws layout proven safe (<= 8.03MB): Zb@0, ZbT@2M, rowsum@4M, Uacc@4M+32K.

#define NR 8192
#define KD 256
#define HD 128

typedef short v8s __attribute__((ext_vector_type(8)));
typedef float v4f __attribute__((ext_vector_type(4)));

static __device__ __forceinline__ ushort f2bf(float f) {
    union { float f; unsigned u; } c; c.f = f;
    unsigned u = c.u;
    u += 0x7fffu + ((u >> 16) & 1u);  // RNE; inputs finite
    return (ushort)(u >> 16);
}
static __device__ __forceinline__ float bf2f(ushort b) {
    union { unsigned u; float f; } c; c.u = ((unsigned)b) << 16; return c.f;
}
static __device__ __forceinline__ unsigned pk2(float a, float b) {
    union { float f; unsigned u; } x, y; x.f = a; y.f = b;
    unsigned ua = x.u + 0x7fffu + ((x.u >> 16) & 1u);
    unsigned ub = y.u + 0x7fffu + ((y.u >> 16) & 1u);
    return (ua >> 16) | (ub & 0xffff0000u);
}

// ---------------- K1: Z = X @ W^T (MFMA, hi/lo bf16 split) — R8 verbatim ----------------
// grid 512 x 256 thr; block = 16 rows of X; wave owns 32 h-columns.
__global__ __launch_bounds__(256) void k_z(const float* __restrict__ X,
                                           const float* __restrict__ W,
                                           ushort* __restrict__ Zb,
                                           ushort* __restrict__ ZbT) {
    __shared__ ushort Xhi[16][264];
    __shared__ ushort Xlo[16][264];
    int tid = threadIdx.x, lane = tid & 63, wave = tid >> 6;
    int lm = lane & 15, lq = lane >> 4;
    int n0 = blockIdx.x * 16;
    int hbase = wave * 32;
    v8s Whi[2][8], Wlo[2][8];
#pragma unroll
    for (int hi = 0; hi < 2; ++hi) {
        const float* wp = W + (hbase + hi * 16 + lm) * KD + lq * 8;
#pragma unroll
        for (int ks = 0; ks < 8; ++ks) {
            float4 w0 = *(const float4*)(wp + ks * 32);
            float4 w1 = *(const float4*)(wp + ks * 32 + 4);
            float wv[8] = {w0.x, w0.y, w0.z, w0.w, w1.x, w1.y, w1.z, w1.w};
#pragma unroll
            for (int j = 0; j < 8; ++j) {
                ushort h = f2bf(wv[j]);
                Whi[hi][ks][j] = (short)h;
                Wlo[hi][ks][j] = (short)f2bf(wv[j] - bf2f(h));
            }
        }
    }
#pragma unroll
    for (int t = 0; t < 4; ++t) {
        int idx = tid + t * 256;
        int r = idx >> 6, c4 = (idx & 63) * 4;
        float4 x = *(const float4*)(X + (size_t)(n0 + r) * KD + c4);
        ushort h0 = f2bf(x.x), h1 = f2bf(x.y), h2 = f2bf(x.z), h3 = f2bf(x.w);
        unsigned a = ((unsigned)h0) | ((unsigned)h1 << 16);
        unsigned b = ((unsigned)h2) | ((unsigned)h3 << 16);
        unsigned c = ((unsigned)f2bf(x.x - bf2f(h0))) | ((unsigned)f2bf(x.y - bf2f(h1)) << 16);
        unsigned d = ((unsigned)f2bf(x.z - bf2f(h2))) | ((unsigned)f2bf(x.w - bf2f(h3)) << 16);
        *(uint2*)&Xhi[r][c4] = make_uint2(a, b);
        *(uint2*)&Xlo[r][c4] = make_uint2(c, d);
    }
    __syncthreads();
    {
        v8s Ah[8], Al[8];
#pragma unroll
        for (int ks = 0; ks < 8; ++ks) {
            Ah[ks] = *(const v8s*)&Xhi[lm][ks * 32 + lq * 8];
            Al[ks] = *(const v8s*)&Xlo[lm][ks * 32 + lq * 8];
        }
        v4f acc[2] = {{0.f, 0.f, 0.f, 0.f}, {0.f, 0.f, 0.f, 0.f}};
#pragma unroll
        for (int ks = 0; ks < 8; ++ks)
#pragma unroll
            for (int hi = 0; hi < 2; ++hi) {
                acc[hi] = __builtin_amdgcn_mfma_f32_16x16x32_bf16(Ah[ks], Whi[hi][ks], acc[hi], 0, 0, 0);
                acc[hi] = __builtin_amdgcn_mfma_f32_16x16x32_bf16(Ah[ks], Wlo[hi][ks], acc[hi], 0, 0, 0);
                acc[hi] = __builtin_amdgcn_mfma_f32_16x16x32_bf16(Al[ks], Whi[hi][ks], acc[hi], 0, 0, 0);
            }
#pragma unroll
        for (int hi = 0; hi < 2; ++hi) {
            int h = hbase + hi * 16 + lm;
            int nb = n0 + lq * 4;
            ushort b0 = f2bf(acc[hi][0]), b1 = f2bf(acc[hi][1]);
            ushort b2 = f2bf(acc[hi][2]), b3 = f2bf(acc[hi][3]);
            Zb[(size_t)(nb + 0) * HD + h] = b0;
            Zb[(size_t)(nb + 1) * HD + h] = b1;
            Zb[(size_t)(nb + 2) * HD + h] = b2;
            Zb[(size_t)(nb + 3) * HD + h] = b3;
            *(uint2*)&ZbT[(size_t)h * NR + nb] =
                make_uint2(((unsigned)b0) | ((unsigned)b1 << 16), ((unsigned)b2) | ((unsigned)b3 << 16));
        }
    }
}

// ---------------- K2: fused rowsum + U (unnormalized out) ----------------
// grid 512 = 64 rb x 8 cs; block = 128 r x (16 iters x 64 c). LDS 70KB -> 2 blocks/CU.
// S phase: wave owns 32 rows (Bfr). U phase: wave = (rh2: 64-r half) x (hh: 64-h half).
__global__ __launch_bounds__(256, 2) void k_sv(const ushort* __restrict__ Zb,
                                               const ushort* __restrict__ ZbT,
                                               float* __restrict__ rowsum,
                                               float* __restrict__ Uacc) {
    __shared__ ushort ZC[2][64][136];
    __shared__ ushort PT[2][128][72];
    int tid = threadIdx.x, lane = tid & 63, wave = tid >> 6;
    int lm = lane & 15, lq = lane >> 4;
    int rb = blockIdx.x >> 3, cs = blockIdx.x & 7;
    int row0 = rb * 128, cstart = cs * 1024;
    int rh2 = wave >> 1, hh = wave & 1;
    v8s Bfr[2][4];  // this wave's 32 rows (S B-operand), one-time global load
#pragma unroll
    for (int ri = 0; ri < 2; ++ri)
#pragma unroll
        for (int ks = 0; ks < 4; ++ks)
            Bfr[ri][ks] =
                *(const v8s*)(Zb + (size_t)(row0 + wave * 32 + ri * 16 + lm) * HD + ks * 32 + lq * 8);
    float rs[2] = {0.f, 0.f};
    v4f U[4][4];  // [rA over 64-r half][hi over 64-h half]
#pragma unroll
    for (int rA = 0; rA < 4; ++rA)
#pragma unroll
        for (int hi = 0; hi < 4; ++hi) U[rA][hi] = (v4f){0.f, 0.f, 0.f, 0.f};

    // prologue: stage ZC[0]
#pragma unroll
    for (int t = 0; t < 4; ++t) {
        int idx = tid + t * 256;
        int r = idx >> 4, c8 = (idx & 15) * 8;
        *(uint4*)&ZC[0][r][c8] = *(const uint4*)(Zb + (size_t)(cstart + r) * HD + c8);
    }
    __syncthreads();

    for (int it = 0; it < 16; ++it) {
        int cur = it & 1;
        int c0 = cstart + it * 64;
        // reg-prefetch next ZC tile (coalesced)
        uint4 sr[4];
        if (it < 15) {
#pragma unroll
            for (int t = 0; t < 4; ++t) {
                int idx = tid + t * 256;
                int r = idx >> 4, c8 = (idx & 15) * 8;
                sr[t] = *(const uint4*)(Zb + (size_t)(c0 + 64 + r) * HD + c8);
            }
        }
        // U-phase B-operand from L2-resident ZbT (issued early; consumed post-barrier)
        v8s Bz[4][2];
#pragma unroll
        for (int hi = 0; hi < 4; ++hi)
#pragma unroll
            for (int ks = 0; ks < 2; ++ks)
                Bz[hi][ks] = *(const v8s*)(ZbT + (size_t)(hh * 64 + hi * 16 + lm) * NR + c0 +
                                           ks * 32 + lq * 8);
        // S phase: S^T = (ZC as A) x (Bfr as B); D: r=lm, c=lq*4+reg
#pragma unroll
        for (int ci = 0; ci < 4; ++ci) {
            v8s Af[4];
#pragma unroll
            for (int ks = 0; ks < 4; ++ks)
                Af[ks] = *(const v8s*)&ZC[cur][ci * 16 + lm][ks * 32 + lq * 8];
            v4f a0 = {0.f, 0.f, 0.f, 0.f}, a1 = {0.f, 0.f, 0.f, 0.f};
#pragma unroll
            for (int ks = 0; ks < 4; ++ks) {
                a0 = __builtin_amdgcn_mfma_f32_16x16x32_bf16(Af[ks], Bfr[0][ks], a0, 0, 0, 0);
                a1 = __builtin_amdgcn_mfma_f32_16x16x32_bf16(Af[ks], Bfr[1][ks], a1, 0, 0, 0);
            }
            int cb = ci * 16 + lq * 4;
            {
                float f0 = fmaxf(a0[0], 0.f), f1 = fmaxf(a0[1], 0.f);
                float f2 = fmaxf(a0[2], 0.f), f3 = fmaxf(a0[3], 0.f);
                rs[0] += f0 + f1 + f2 + f3;
                *(uint2*)&PT[cur][wave * 32 + lm][cb] = make_uint2(pk2(f0, f1), pk2(f2, f3));
            }
            {
                float f0 = fmaxf(a1[0], 0.f), f1 = fmaxf(a1[1], 0.f);
                float f2 = fmaxf(a1[2], 0.f), f3 = fmaxf(a1[3], 0.f);
                rs[1] += f0 + f1 + f2 + f3;
                *(uint2*)&PT[cur][wave * 32 + 16 + lm][cb] = make_uint2(pk2(f0, f1), pk2(f2, f3));
            }
        }
        // write next ZC tile (other parity; prev readers done before prev barrier)
        if (it < 15) {
#pragma unroll
            for (int t = 0; t < 4; ++t) {
                int idx = tid + t * 256;
                int r = idx >> 4, c8 = (idx & 15) * 8;
                *(uint4*)&ZC[cur ^ 1][r][c8] = sr[t];
            }
        }
        __syncthreads();  // PT[cur] + ZC[nxt] ready
        // U phase: U[r][h] += P[r][c] * Z[c][h]; A = PT frag, B = Bz regs
#pragma unroll
        for (int ks = 0; ks < 2; ++ks) {
            v8s Pf[4];
#pragma unroll
            for (int rA = 0; rA < 4; ++rA)
                Pf[rA] = *(const v8s*)&PT[cur][rh2 * 64 + rA * 16 + lm][ks * 32 + lq * 8];
#pragma unroll
            for (int hi = 0; hi < 4; ++hi)
#pragma unroll
                for (int rA = 0; rA < 4; ++rA)
                    U[rA][hi] = __builtin_amdgcn_mfma_f32_16x16x32_bf16(Pf[rA], Bz[hi][ks], U[rA][hi], 0, 0, 0);
        }
    }
    // rowsum: reduce over lq groups, one atomic per row per wave
#pragma unroll
    for (int ri = 0; ri < 2; ++ri) {
        float v = rs[ri];
        v += __shfl_xor(v, 16, 64);
        v += __shfl_xor(v, 32, 64);
        if (lq == 0) atomicAdd(&rowsum[row0 + wave * 32 + ri * 16 + lm], v);
    }
    // U partials: D layout -> r = rh2*64+rA*16+lq*4+j, h = hh*64+hi*16+lm; 8 adds per address
    float* ub = Uacc + (size_t)(row0 + rh2 * 64) * HD + hh * 64;
#pragma unroll
    for (int rA = 0; rA < 4; ++rA)
#pragma unroll
        for (int hi = 0; hi < 4; ++hi)
#pragma unroll
            for (int j = 0; j < 4; ++j)
                atomicAdd(&ub[(size_t)(rA * 16 + lq * 4 + j) * HD + hi * 16 + lm], U[rA][hi][j]);
}

// ---------------- K3: A writer — zero LDS, zero barriers (R2-proven indexing) ----------------
// grid 2048 = 128 rb (64 r) x 16 cs (512 c); 8 iters x 64 c. Pure write stream.
__global__ __launch_bounds__(256, 4) void k_a(const ushort* __restrict__ Zb,
                                              const float* __restrict__ rowsum,
                                              float* __restrict__ Ap) {
    int tid = threadIdx.x, lane = tid & 63, wave = tid >> 6;
    int lm = lane & 15, lq = lane >> 4;
    int rb = blockIdx.x >> 4, cs = blockIdx.x & 15;
    int row0 = rb * 64, colb = cs * 512;
    int wr2 = wave >> 1, wc2 = wave & 1;
    v8s Bfr[2][4];  // one-time scattered loads (L2)
#pragma unroll
    for (int ri = 0; ri < 2; ++ri)
#pragma unroll
        for (int ks = 0; ks < 4; ++ks)
            Bfr[ri][ks] =
                *(const v8s*)(Zb + (size_t)(row0 + wr2 * 32 + ri * 16 + lm) * HD + ks * 32 + lq * 8);
    float rsv[2];
#pragma unroll
    for (int ri = 0; ri < 2; ++ri)
        rsv[ri] = 1.0f / (rowsum[row0 + wr2 * 32 + ri * 16 + lm] + 1e-6f);
    const ushort* afp = Zb + (size_t)(colb + wc2 * 32 + lm) * HD + lq * 8;
    float* ap0 = Ap + (size_t)(row0 + wr2 * 32 + lm) * NR + colb + wc2 * 32 + lq * 4;
    float* ap1 = ap0 + (size_t)16 * NR;
    for (int it = 0; it < 8; ++it) {
#pragma unroll
        for (int ci = 0; ci < 2; ++ci) {
            v8s Af[4];
#pragma unroll
            for (int ks = 0; ks < 4; ++ks)
                Af[ks] = *(const v8s*)(afp + (size_t)(ci * 16) * HD + ks * 32);
            v4f S0 = {0.f, 0.f, 0.f, 0.f}, S1 = {0.f, 0.f, 0.f, 0.f};
#pragma unroll
            for (int ks = 0; ks < 4; ++ks) {
                S0 = __builtin_amdgcn_mfma_f32_16x16x32_bf16(Af[ks], Bfr[0][ks], S0, 0, 0, 0);
                S1 = __builtin_amdgcn_mfma_f32_16x16x32_bf16(Af[ks], Bfr[1][ks], S1, 0, 0, 0);
            }
            v4f av;
            av[0] = fmaxf(S0[0], 0.f) * rsv[0]; av[1] = fmaxf(S0[1], 0.f) * rsv[0];
            av[2] = fmaxf(S0[2], 0.f) * rsv[0]; av[3] = fmaxf(S0[3], 0.f) * rsv[0];
            __builtin_nontemporal_store(av, (v4f*)(ap0 + ci * 16));
            av[0] = fmaxf(S1[0], 0.f) * rsv[1]; av[1] = fmaxf(S1[1], 0.f) * rsv[1];
            av[2] = fmaxf(S1[2], 0.f) * rsv[1]; av[3] = fmaxf(S1[3], 0.f) * rsv[1];
            __builtin_nontemporal_store(av, (v4f*)(ap1 + ci * 16));
        }
        afp += (size_t)64 * HD;
        ap0 += 64;
        ap1 += 64;
    }
}

// ---------------- K4: out = Uacc * rsinv ----------------
__global__ __launch_bounds__(256) void k_out(const float* __restrict__ Uacc,
                                             const float* __restrict__ rowsum,
                                             float* __restrict__ outp) {
    int idx = blockIdx.x * 256 + threadIdx.x;  // float4 index, 262144 total
    int r = idx >> 5, h4 = (idx & 31) * 4;
    float rsv = 1.0f / (rowsum[r] + 1e-6f);
    size_t o = (size_t)r * HD + h4;
    float4 v = *(const float4*)(Uacc + o);
    float4 s = make_float4(v.x * rsv, v.y * rsv, v.z * rsv, v.w * rsv);
    *(float4*)(outp + o) = s;
}

extern "C" void kernel_launch(void* const* d_in, const int* in_sizes, int n_in,
                              void* d_out, int out_size, void* d_ws, size_t ws_size,
                              hipStream_t stream) {
    (void)in_sizes; (void)n_in; (void)out_size; (void)ws_size;
    const float* X = (const float*)d_in[0];
    const float* W = (const float*)d_in[1];
    float* outp = (float*)d_out;
    float* Ap = outp + (size_t)NR * HD;  // A follows out in d_out
    char* ws = (char*)d_ws;
    ushort* Zb = (ushort*)ws;                                   // 2 MB
    ushort* ZbT = (ushort*)(ws + (size_t)NR * HD * 2);          // 2 MB
    float* rowsum = (float*)(ws + (size_t)NR * HD * 4);         // 32 KB @ 4MB
    float* Uacc = (float*)(ws + (size_t)NR * HD * 4 + NR * 4);  // 4 MB @ 4MB+32KB (proven region)

    (void)hipMemsetAsync(rowsum, 0, NR * sizeof(float), stream);
    (void)hipMemsetAsync(Uacc, 0, (size_t)NR * HD * sizeof(float), stream);
    k_z<<<dim3(NR / 16), dim3(256), 0, stream>>>(X, W, Zb, ZbT);
    k_sv<<<dim3(512), dim3(256), 0, stream>>>(Zb, ZbT, rowsum, Uacc);
    k_a<<<dim3(2048), dim3(256), 0, stream>>>(Zb, rowsum, Ap);
    k_out<<<dim3(1024), dim3(256), 0, stream>>>(Uacc, rowsum, outp);
}

// Round 10
// 361.073 us; speedup vs baseline: 1.0710x; 1.0710x over previous
//
#include <hip/hip_runtime.h>

// AdaptiveGraph on MI355X — v10: R8 (362us, best) + ONE change: raw lgkmcnt-only barrier
// in k_main's loop. __syncthreads emits s_waitcnt vmcnt(0) lgkmcnt(0): at each of the 16
// in-loop barriers every wave waited on (a) 8 scattered Bz loads not needed until the
// post-barrier U phase and (b) last iter's nontemporal HBM stores (needed by nobody).
// Only true cross-wave hazard is LDS (PT/ZC ds_writes) -> lgkmcnt(0)+s_barrier suffices.
// k_z / k_rowsum / epilogue / launcher: byte-identical to R8.

#define NR 8192
#define KD 256
#define HD 128

typedef short v8s __attribute__((ext_vector_type(8)));
typedef float v4f __attribute__((ext_vector_type(4)));

static __device__ __forceinline__ ushort f2bf(float f) {
    union { float f; unsigned u; } c; c.f = f;
    unsigned u = c.u;
    u += 0x7fffu + ((u >> 16) & 1u);  // RNE; inputs finite
    return (ushort)(u >> 16);
}
static __device__ __forceinline__ float bf2f(ushort b) {
    union { unsigned u; float f; } c; c.u = ((unsigned)b) << 16; return c.f;
}
static __device__ __forceinline__ unsigned pk2(float a, float b) {
    union { float f; unsigned u; } x, y; x.f = a; y.f = b;
    unsigned ua = x.u + 0x7fffu + ((x.u >> 16) & 1u);
    unsigned ub = y.u + 0x7fffu + ((y.u >> 16) & 1u);
    return (ua >> 16) | (ub & 0xffff0000u);
}

// LDS-visibility barrier: wait own ds ops, then block-barrier. No vmcnt drain.
static __device__ __forceinline__ void lds_barrier() {
    asm volatile("s_waitcnt lgkmcnt(0)" ::: "memory");
    __builtin_amdgcn_s_barrier();
}

// ---------------- K1: Z = X @ W^T (MFMA, hi/lo bf16 split) — R8 verbatim ----------------
// grid 512 x 256 thr; block = 16 rows of X; wave owns 32 h-columns.
__global__ __launch_bounds__(256) void k_z(const float* __restrict__ X,
                                           const float* __restrict__ W,
                                           ushort* __restrict__ Zb,
                                           ushort* __restrict__ ZbT) {
    __shared__ ushort Xhi[16][264];
    __shared__ ushort Xlo[16][264];
    int tid = threadIdx.x, lane = tid & 63, wave = tid >> 6;
    int lm = lane & 15, lq = lane >> 4;
    int n0 = blockIdx.x * 16;
    int hbase = wave * 32;
    v8s Whi[2][8], Wlo[2][8];
#pragma unroll
    for (int hi = 0; hi < 2; ++hi) {
        const float* wp = W + (hbase + hi * 16 + lm) * KD + lq * 8;
#pragma unroll
        for (int ks = 0; ks < 8; ++ks) {
            float4 w0 = *(const float4*)(wp + ks * 32);
            float4 w1 = *(const float4*)(wp + ks * 32 + 4);
            float wv[8] = {w0.x, w0.y, w0.z, w0.w, w1.x, w1.y, w1.z, w1.w};
#pragma unroll
            for (int j = 0; j < 8; ++j) {
                ushort h = f2bf(wv[j]);
                Whi[hi][ks][j] = (short)h;
                Wlo[hi][ks][j] = (short)f2bf(wv[j] - bf2f(h));
            }
        }
    }
#pragma unroll
    for (int t = 0; t < 4; ++t) {
        int idx = tid + t * 256;
        int r = idx >> 6, c4 = (idx & 63) * 4;
        float4 x = *(const float4*)(X + (size_t)(n0 + r) * KD + c4);
        ushort h0 = f2bf(x.x), h1 = f2bf(x.y), h2 = f2bf(x.z), h3 = f2bf(x.w);
        unsigned a = ((unsigned)h0) | ((unsigned)h1 << 16);
        unsigned b = ((unsigned)h2) | ((unsigned)h3 << 16);
        unsigned c = ((unsigned)f2bf(x.x - bf2f(h0))) | ((unsigned)f2bf(x.y - bf2f(h1)) << 16);
        unsigned d = ((unsigned)f2bf(x.z - bf2f(h2))) | ((unsigned)f2bf(x.w - bf2f(h3)) << 16);
        *(uint2*)&Xhi[r][c4] = make_uint2(a, b);
        *(uint2*)&Xlo[r][c4] = make_uint2(c, d);
    }
    __syncthreads();
    {
        v8s Ah[8], Al[8];
#pragma unroll
        for (int ks = 0; ks < 8; ++ks) {
            Ah[ks] = *(const v8s*)&Xhi[lm][ks * 32 + lq * 8];
            Al[ks] = *(const v8s*)&Xlo[lm][ks * 32 + lq * 8];
        }
        v4f acc[2] = {{0.f, 0.f, 0.f, 0.f}, {0.f, 0.f, 0.f, 0.f}};
#pragma unroll
        for (int ks = 0; ks < 8; ++ks)
#pragma unroll
            for (int hi = 0; hi < 2; ++hi) {
                acc[hi] = __builtin_amdgcn_mfma_f32_16x16x32_bf16(Ah[ks], Whi[hi][ks], acc[hi], 0, 0, 0);
                acc[hi] = __builtin_amdgcn_mfma_f32_16x16x32_bf16(Ah[ks], Wlo[hi][ks], acc[hi], 0, 0, 0);
                acc[hi] = __builtin_amdgcn_mfma_f32_16x16x32_bf16(Al[ks], Whi[hi][ks], acc[hi], 0, 0, 0);
            }
#pragma unroll
        for (int hi = 0; hi < 2; ++hi) {
            int h = hbase + hi * 16 + lm;
            int nb = n0 + lq * 4;
            ushort b0 = f2bf(acc[hi][0]), b1 = f2bf(acc[hi][1]);
            ushort b2 = f2bf(acc[hi][2]), b3 = f2bf(acc[hi][3]);
            Zb[(size_t)(nb + 0) * HD + h] = b0;
            Zb[(size_t)(nb + 1) * HD + h] = b1;
            Zb[(size_t)(nb + 2) * HD + h] = b2;
            Zb[(size_t)(nb + 3) * HD + h] = b3;
            *(uint2*)&ZbT[(size_t)h * NR + nb] =
                make_uint2(((unsigned)b0) | ((unsigned)b1 << 16), ((unsigned)b2) | ((unsigned)b3 << 16));
        }
    }
}

// ---------------- K2: rowsum — 1 barrier/iter (R8 verbatim) ----------------
// grid 1024 = 64 rb x 16 cs; block = 128 rows x (8 iters x 64 cols); wave owns 32 rows.
__global__ __launch_bounds__(256) void k_rowsum(const ushort* __restrict__ Zb,
                                                float* __restrict__ rowsum) {
    __shared__ ushort ZC[2][64][136];
    int tid = threadIdx.x, lane = tid & 63, wave = tid >> 6;
    int lm = lane & 15, lq = lane >> 4;
    int rb = blockIdx.x >> 4, cs = blockIdx.x & 15;
    int row0 = rb * 128, cstart = cs * 512;
    v8s Bfr[2][4];  // this wave's 32 rows (B-operand), one-time global load
#pragma unroll
    for (int ri = 0; ri < 2; ++ri)
#pragma unroll
        for (int ks = 0; ks < 4; ++ks)
            Bfr[ri][ks] =
                *(const v8s*)(Zb + (size_t)(row0 + wave * 32 + ri * 16 + lm) * HD + ks * 32 + lq * 8);
    float rs[2] = {0.f, 0.f};
#pragma unroll
    for (int t = 0; t < 4; ++t) {
        int idx = tid + t * 256;
        int r = idx >> 4, c8 = (idx & 15) * 8;
        *(uint4*)&ZC[0][r][c8] = *(const uint4*)(Zb + (size_t)(cstart + r) * HD + c8);
    }
    __syncthreads();
    for (int it = 0; it < 8; ++it) {
        int cur = it & 1;
        int c0 = cstart + it * 64;
        uint4 sr[4];
        if (it < 7) {
#pragma unroll
            for (int t = 0; t < 4; ++t) {
                int idx = tid + t * 256;
                int r = idx >> 4, c8 = (idx & 15) * 8;
                sr[t] = *(const uint4*)(Zb + (size_t)(c0 + 64 + r) * HD + c8);
            }
        }
#pragma unroll
        for (int ci = 0; ci < 4; ++ci) {
            v8s Af[4];
#pragma unroll
            for (int ks = 0; ks < 4; ++ks)
                Af[ks] = *(const v8s*)&ZC[cur][ci * 16 + lm][ks * 32 + lq * 8];
            v4f a0 = {0.f, 0.f, 0.f, 0.f}, a1 = {0.f, 0.f, 0.f, 0.f};
#pragma unroll
            for (int ks = 0; ks < 4; ++ks) {
                a0 = __builtin_amdgcn_mfma_f32_16x16x32_bf16(Af[ks], Bfr[0][ks], a0, 0, 0, 0);
                a1 = __builtin_amdgcn_mfma_f32_16x16x32_bf16(Af[ks], Bfr[1][ks], a1, 0, 0, 0);
            }
            rs[0] += fmaxf(a0[0], 0.f) + fmaxf(a0[1], 0.f) + fmaxf(a0[2], 0.f) + fmaxf(a0[3], 0.f);
            rs[1] += fmaxf(a1[0], 0.f) + fmaxf(a1[1], 0.f) + fmaxf(a1[2], 0.f) + fmaxf(a1[3], 0.f);
        }
        if (it < 7) {
#pragma unroll
            for (int t = 0; t < 4; ++t) {
                int idx = tid + t * 256;
                int r = idx >> 4, c8 = (idx & 15) * 8;
                *(uint4*)&ZC[cur ^ 1][r][c8] = sr[t];
            }
        }
        __syncthreads();
    }
#pragma unroll
    for (int ri = 0; ri < 2; ++ri) {
        float v = rs[ri];
        v += __shfl_xor(v, 16, 64);
        v += __shfl_xor(v, 32, 64);
        if (lq == 0) atomicAdd(&rowsum[row0 + wave * 32 + ri * 16 + lm], v);
    }
}

// ---------------- K3: A write + out accumulate — raw LDS barrier ----------------
// grid 1024 = 128 rb x 8 cs; block tile 64r x (16 iters x 64c). LDS 53.2KB -> 3 blocks/CU.
__global__ __launch_bounds__(256) void k_main(const ushort* __restrict__ Zb,
                                              const ushort* __restrict__ ZbT,
                                              const float* __restrict__ rowsum,
                                              float* __restrict__ outp,
                                              float* __restrict__ Ap) {
    __shared__ ushort ZC[2][64][136];
    __shared__ ushort PT[2][64][72];
    int tid = threadIdx.x, lane = tid & 63, wave = tid >> 6;
    int lm = lane & 15, lq = lane >> 4;
    int rb = blockIdx.x >> 3, cs = blockIdx.x & 7;
    int row0 = rb * 64, colb = cs * 1024;
    int wr2 = wave >> 1, wc2 = wave & 1;
    v8s Bfr[2][4];  // one-time reg B-frags (rows of this strip)
#pragma unroll
    for (int ri = 0; ri < 2; ++ri)
#pragma unroll
        for (int ks = 0; ks < 4; ++ks)
            Bfr[ri][ks] =
                *(const v8s*)(Zb + (size_t)(row0 + wr2 * 32 + ri * 16 + lm) * HD + ks * 32 + lq * 8);
    float rsv[2];
#pragma unroll
    for (int ri = 0; ri < 2; ++ri)
        rsv[ri] = 1.0f / (rowsum[row0 + wr2 * 32 + ri * 16 + lm] + 1e-6f);
    v4f U[2][4];
#pragma unroll
    for (int ri = 0; ri < 2; ++ri)
#pragma unroll
        for (int hi = 0; hi < 4; ++hi) U[ri][hi] = (v4f){0.f, 0.f, 0.f, 0.f};

    // prologue: stage ZC[0]
#pragma unroll
    for (int t = 0; t < 4; ++t) {
        int idx = tid + t * 256;
        int r = idx >> 4, c8 = (idx & 15) * 8;
        *(uint4*)&ZC[0][r][c8] = *(const uint4*)(Zb + (size_t)(colb + r) * HD + c8);
    }
    __syncthreads();

    float* ap0 = Ap + (size_t)(row0 + wr2 * 32 + lm) * NR + colb + wc2 * 32 + lq * 4;
    float* ap1 = ap0 + (size_t)16 * NR;

    for (int it = 0; it < 16; ++it) {
        int cur = it & 1;
        int c0 = colb + it * 64;
        uint4 sr[4];
        if (it < 15) {
#pragma unroll
            for (int t = 0; t < 4; ++t) {
                int idx = tid + t * 256;
                int r = idx >> 4, c8 = (idx & 15) * 8;
                sr[t] = *(const uint4*)(Zb + (size_t)(c0 + 64 + r) * HD + c8);
            }
        }
        v8s Bz[4][2];
#pragma unroll
        for (int hi = 0; hi < 4; ++hi)
#pragma unroll
            for (int ks = 0; ks < 2; ++ks)
                Bz[hi][ks] = *(const v8s*)(ZbT + (size_t)(wc2 * 64 + hi * 16 + lm) * NR + c0 +
                                           ks * 32 + lq * 8);
        v4f avst[2][2];  // deferred A-store values [ci][r-half]
#pragma unroll
        for (int ci = 0; ci < 2; ++ci) {
            v8s Af[4];
#pragma unroll
            for (int ks = 0; ks < 4; ++ks)
                Af[ks] = *(const v8s*)&ZC[cur][wc2 * 32 + ci * 16 + lm][ks * 32 + lq * 8];
            v4f S0 = {0.f, 0.f, 0.f, 0.f}, S1 = {0.f, 0.f, 0.f, 0.f};
#pragma unroll
            for (int ks = 0; ks < 4; ++ks) {
                S0 = __builtin_amdgcn_mfma_f32_16x16x32_bf16(Af[ks], Bfr[0][ks], S0, 0, 0, 0);
                S1 = __builtin_amdgcn_mfma_f32_16x16x32_bf16(Af[ks], Bfr[1][ks], S1, 0, 0, 0);
            }
            int cb = wc2 * 32 + ci * 16 + lq * 4;
            {
                v4f av;
                av[0] = fmaxf(S0[0], 0.f) * rsv[0]; av[1] = fmaxf(S0[1], 0.f) * rsv[0];
                av[2] = fmaxf(S0[2], 0.f) * rsv[0]; av[3] = fmaxf(S0[3], 0.f) * rsv[0];
                avst[ci][0] = av;
                *(uint2*)&PT[cur][wr2 * 32 + lm][cb] = make_uint2(pk2(av[0], av[1]), pk2(av[2], av[3]));
            }
            {
                v4f av;
                av[0] = fmaxf(S1[0], 0.f) * rsv[1]; av[1] = fmaxf(S1[1], 0.f) * rsv[1];
                av[2] = fmaxf(S1[2], 0.f) * rsv[1]; av[3] = fmaxf(S1[3], 0.f) * rsv[1];
                avst[ci][1] = av;
                *(uint2*)&PT[cur][wr2 * 32 + 16 + lm][cb] =
                    make_uint2(pk2(av[0], av[1]), pk2(av[2], av[3]));
            }
        }
        if (it < 15) {
#pragma unroll
            for (int t = 0; t < 4; ++t) {
                int idx = tid + t * 256;
                int r = idx >> 4, c8 = (idx & 15) * 8;
                *(uint4*)&ZC[cur ^ 1][r][c8] = sr[t];
            }
        }
        // THE barrier: LDS-only drain. Bz loads and last iter's nt stores stay in flight
        // (Bz is register-dep-waited in the U phase; stores are waited by nobody in-loop).
        lds_barrier();
#pragma unroll
        for (int ci = 0; ci < 2; ++ci) {
            __builtin_nontemporal_store(avst[ci][0], (v4f*)(ap0 + ci * 16));
            __builtin_nontemporal_store(avst[ci][1], (v4f*)(ap1 + ci * 16));
        }
#pragma unroll
        for (int ks = 0; ks < 2; ++ks) {
            v8s P0 = *(const v8s*)&PT[cur][wr2 * 32 + lm][ks * 32 + lq * 8];
            v8s P1 = *(const v8s*)&PT[cur][wr2 * 32 + 16 + lm][ks * 32 + lq * 8];
#pragma unroll
            for (int hi = 0; hi < 4; ++hi) {
                U[0][hi] = __builtin_amdgcn_mfma_f32_16x16x32_bf16(P0, Bz[hi][ks], U[0][hi], 0, 0, 0);
                U[1][hi] = __builtin_amdgcn_mfma_f32_16x16x32_bf16(P1, Bz[hi][ks], U[1][hi], 0, 0, 0);
            }
        }
        ap0 += 64;
        ap1 += 64;
    }
#pragma unroll
    for (int ri = 0; ri < 2; ++ri)
#pragma unroll
        for (int hi = 0; hi < 4; ++hi)
#pragma unroll
            for (int j = 0; j < 4; ++j)
                atomicAdd(&outp[(size_t)(row0 + wr2 * 32 + ri * 16 + lq * 4 + j) * HD +
                                wc2 * 64 + hi * 16 + lm],
                          U[ri][hi][j]);
}

extern "C" void kernel_launch(void* const* d_in, const int* in_sizes, int n_in,
                              void* d_out, int out_size, void* d_ws, size_t ws_size,
                              hipStream_t stream) {
    (void)in_sizes; (void)n_in; (void)out_size; (void)ws_size;
    const float* X = (const float*)d_in[0];
    const float* W = (const float*)d_in[1];
    float* outp = (float*)d_out;
    float* Ap = outp + (size_t)NR * HD;  // A follows out in d_out
    char* ws = (char*)d_ws;
    ushort* Zb = (ushort*)ws;                                 // 2 MB
    ushort* ZbT = (ushort*)(ws + (size_t)NR * HD * 2);        // 2 MB
    float* rowsum = (float*)(ws + (size_t)NR * HD * 4);       // 32 KB  (ws total 8.03MB, proven)

    (void)hipMemsetAsync(outp, 0, (size_t)NR * HD * sizeof(float), stream);
    (void)hipMemsetAsync(rowsum, 0, NR * sizeof(float), stream);
    k_z<<<dim3(NR / 16), dim3(256), 0, stream>>>(X, W, Zb, ZbT);
    k_rowsum<<<dim3(1024), dim3(256), 0, stream>>>(Zb, rowsum);
    k_main<<<dim3(1024), dim3(256), 0, stream>>>(Zb, ZbT, rowsum, outp, Ap);
}

// Round 12
// 345.594 us; speedup vs baseline: 1.1190x; 1.0448x over previous
//
#include <hip/hip_runtime.h>

// AdaptiveGraph on MI355X — v12: R11 (TA-scatter surgery) with the compile fix:
// __builtin_nontemporal_store needs a clang ext_vector type, not HIP's float2 class.
// Evidence base (R10): lgkm-only barrier NEUTRAL -> not barrier-drain-bound. All
// counters low (Mfma 8%, VALU 10%, HBM 27%) -> TA/issue-bound: scattered Bz loads
// (8 instr x 16 segments, 2x duplicated) + scattered A-stores (4 instr x 16 segs).
// Fix 1: U-phase remap — wave owns a 32-h quarter: Bz 8->4 loads, no duplication.
// Fix 2: A-stores from PT (bf16(A)) post-barrier: lds read + cvt + nt store,
//        2x256B contiguous segments/instr. A gains bf16 rounding (~1e-6 abs, ok).
// k_z / k_rowsum / launcher byte-identical to R10.

#define NR 8192
#define KD 256
#define HD 128

typedef short v8s __attribute__((ext_vector_type(8)));
typedef float v4f __attribute__((ext_vector_type(4)));
typedef float v2f __attribute__((ext_vector_type(2)));

static __device__ __forceinline__ ushort f2bf(float f) {
    union { float f; unsigned u; } c; c.f = f;
    unsigned u = c.u;
    u += 0x7fffu + ((u >> 16) & 1u);  // RNE; inputs finite
    return (ushort)(u >> 16);
}
static __device__ __forceinline__ float bf2f(ushort b) {
    union { unsigned u; float f; } c; c.u = ((unsigned)b) << 16; return c.f;
}
static __device__ __forceinline__ unsigned pk2(float a, float b) {
    union { float f; unsigned u; } x, y; x.f = a; y.f = b;
    unsigned ua = x.u + 0x7fffu + ((x.u >> 16) & 1u);
    unsigned ub = y.u + 0x7fffu + ((y.u >> 16) & 1u);
    return (ua >> 16) | (ub & 0xffff0000u);
}

// LDS-visibility barrier: wait own ds ops, then block-barrier. No vmcnt drain.
static __device__ __forceinline__ void lds_barrier() {
    asm volatile("s_waitcnt lgkmcnt(0)" ::: "memory");
    __builtin_amdgcn_s_barrier();
}

// ---------------- K1: Z = X @ W^T (MFMA, hi/lo bf16 split) — R10 verbatim ----------------
__global__ __launch_bounds__(256) void k_z(const float* __restrict__ X,
                                           const float* __restrict__ W,
                                           ushort* __restrict__ Zb,
                                           ushort* __restrict__ ZbT) {
    __shared__ ushort Xhi[16][264];
    __shared__ ushort Xlo[16][264];
    int tid = threadIdx.x, lane = tid & 63, wave = tid >> 6;
    int lm = lane & 15, lq = lane >> 4;
    int n0 = blockIdx.x * 16;
    int hbase = wave * 32;
    v8s Whi[2][8], Wlo[2][8];
#pragma unroll
    for (int hi = 0; hi < 2; ++hi) {
        const float* wp = W + (hbase + hi * 16 + lm) * KD + lq * 8;
#pragma unroll
        for (int ks = 0; ks < 8; ++ks) {
            float4 w0 = *(const float4*)(wp + ks * 32);
            float4 w1 = *(const float4*)(wp + ks * 32 + 4);
            float wv[8] = {w0.x, w0.y, w0.z, w0.w, w1.x, w1.y, w1.z, w1.w};
#pragma unroll
            for (int j = 0; j < 8; ++j) {
                ushort h = f2bf(wv[j]);
                Whi[hi][ks][j] = (short)h;
                Wlo[hi][ks][j] = (short)f2bf(wv[j] - bf2f(h));
            }
        }
    }
#pragma unroll
    for (int t = 0; t < 4; ++t) {
        int idx = tid + t * 256;
        int r = idx >> 6, c4 = (idx & 63) * 4;
        float4 x = *(const float4*)(X + (size_t)(n0 + r) * KD + c4);
        ushort h0 = f2bf(x.x), h1 = f2bf(x.y), h2 = f2bf(x.z), h3 = f2bf(x.w);
        unsigned a = ((unsigned)h0) | ((unsigned)h1 << 16);
        unsigned b = ((unsigned)h2) | ((unsigned)h3 << 16);
        unsigned c = ((unsigned)f2bf(x.x - bf2f(h0))) | ((unsigned)f2bf(x.y - bf2f(h1)) << 16);
        unsigned d = ((unsigned)f2bf(x.z - bf2f(h2))) | ((unsigned)f2bf(x.w - bf2f(h3)) << 16);
        *(uint2*)&Xhi[r][c4] = make_uint2(a, b);
        *(uint2*)&Xlo[r][c4] = make_uint2(c, d);
    }
    __syncthreads();
    {
        v8s Ah[8], Al[8];
#pragma unroll
        for (int ks = 0; ks < 8; ++ks) {
            Ah[ks] = *(const v8s*)&Xhi[lm][ks * 32 + lq * 8];
            Al[ks] = *(const v8s*)&Xlo[lm][ks * 32 + lq * 8];
        }
        v4f acc[2] = {{0.f, 0.f, 0.f, 0.f}, {0.f, 0.f, 0.f, 0.f}};
#pragma unroll
        for (int ks = 0; ks < 8; ++ks)
#pragma unroll
            for (int hi = 0; hi < 2; ++hi) {
                acc[hi] = __builtin_amdgcn_mfma_f32_16x16x32_bf16(Ah[ks], Whi[hi][ks], acc[hi], 0, 0, 0);
                acc[hi] = __builtin_amdgcn_mfma_f32_16x16x32_bf16(Ah[ks], Wlo[hi][ks], acc[hi], 0, 0, 0);
                acc[hi] = __builtin_amdgcn_mfma_f32_16x16x32_bf16(Al[ks], Whi[hi][ks], acc[hi], 0, 0, 0);
            }
#pragma unroll
        for (int hi = 0; hi < 2; ++hi) {
            int h = hbase + hi * 16 + lm;
            int nb = n0 + lq * 4;
            ushort b0 = f2bf(acc[hi][0]), b1 = f2bf(acc[hi][1]);
            ushort b2 = f2bf(acc[hi][2]), b3 = f2bf(acc[hi][3]);
            Zb[(size_t)(nb + 0) * HD + h] = b0;
            Zb[(size_t)(nb + 1) * HD + h] = b1;
            Zb[(size_t)(nb + 2) * HD + h] = b2;
            Zb[(size_t)(nb + 3) * HD + h] = b3;
            *(uint2*)&ZbT[(size_t)h * NR + nb] =
                make_uint2(((unsigned)b0) | ((unsigned)b1 << 16), ((unsigned)b2) | ((unsigned)b3 << 16));
        }
    }
}

// ---------------- K2: rowsum — R10 verbatim ----------------
__global__ __launch_bounds__(256) void k_rowsum(const ushort* __restrict__ Zb,
                                                float* __restrict__ rowsum) {
    __shared__ ushort ZC[2][64][136];
    int tid = threadIdx.x, lane = tid & 63, wave = tid >> 6;
    int lm = lane & 15, lq = lane >> 4;
    int rb = blockIdx.x >> 4, cs = blockIdx.x & 15;
    int row0 = rb * 128, cstart = cs * 512;
    v8s Bfr[2][4];
#pragma unroll
    for (int ri = 0; ri < 2; ++ri)
#pragma unroll
        for (int ks = 0; ks < 4; ++ks)
            Bfr[ri][ks] =
                *(const v8s*)(Zb + (size_t)(row0 + wave * 32 + ri * 16 + lm) * HD + ks * 32 + lq * 8);
    float rs[2] = {0.f, 0.f};
#pragma unroll
    for (int t = 0; t < 4; ++t) {
        int idx = tid + t * 256;
        int r = idx >> 4, c8 = (idx & 15) * 8;
        *(uint4*)&ZC[0][r][c8] = *(const uint4*)(Zb + (size_t)(cstart + r) * HD + c8);
    }
    __syncthreads();
    for (int it = 0; it < 8; ++it) {
        int cur = it & 1;
        int c0 = cstart + it * 64;
        uint4 sr[4];
        if (it < 7) {
#pragma unroll
            for (int t = 0; t < 4; ++t) {
                int idx = tid + t * 256;
                int r = idx >> 4, c8 = (idx & 15) * 8;
                sr[t] = *(const uint4*)(Zb + (size_t)(c0 + 64 + r) * HD + c8);
            }
        }
#pragma unroll
        for (int ci = 0; ci < 4; ++ci) {
            v8s Af[4];
#pragma unroll
            for (int ks = 0; ks < 4; ++ks)
                Af[ks] = *(const v8s*)&ZC[cur][ci * 16 + lm][ks * 32 + lq * 8];
            v4f a0 = {0.f, 0.f, 0.f, 0.f}, a1 = {0.f, 0.f, 0.f, 0.f};
#pragma unroll
            for (int ks = 0; ks < 4; ++ks) {
                a0 = __builtin_amdgcn_mfma_f32_16x16x32_bf16(Af[ks], Bfr[0][ks], a0, 0, 0, 0);
                a1 = __builtin_amdgcn_mfma_f32_16x16x32_bf16(Af[ks], Bfr[1][ks], a1, 0, 0, 0);
            }
            rs[0] += fmaxf(a0[0], 0.f) + fmaxf(a0[1], 0.f) + fmaxf(a0[2], 0.f) + fmaxf(a0[3], 0.f);
            rs[1] += fmaxf(a1[0], 0.f) + fmaxf(a1[1], 0.f) + fmaxf(a1[2], 0.f) + fmaxf(a1[3], 0.f);
        }
        if (it < 7) {
#pragma unroll
            for (int t = 0; t < 4; ++t) {
                int idx = tid + t * 256;
                int r = idx >> 4, c8 = (idx & 15) * 8;
                *(uint4*)&ZC[cur ^ 1][r][c8] = sr[t];
            }
        }
        __syncthreads();
    }
#pragma unroll
    for (int ri = 0; ri < 2; ++ri) {
        float v = rs[ri];
        v += __shfl_xor(v, 16, 64);
        v += __shfl_xor(v, 32, 64);
        if (lq == 0) atomicAdd(&rowsum[row0 + wave * 32 + ri * 16 + lm], v);
    }
}

// ---------------- K3: A write + out accumulate — TA-scatter-fixed ----------------
// grid 1024 = 128 rb x 8 cs; block tile 64r x (16 iters x 64c). LDS 52KB -> 3 blocks/CU.
__global__ __launch_bounds__(256) void k_main(const ushort* __restrict__ Zb,
                                              const ushort* __restrict__ ZbT,
                                              const float* __restrict__ rowsum,
                                              float* __restrict__ outp,
                                              float* __restrict__ Ap) {
    __shared__ ushort ZC[2][64][136];
    __shared__ ushort PT[2][64][72];
    int tid = threadIdx.x, lane = tid & 63, wave = tid >> 6;
    int lm = lane & 15, lq = lane >> 4;
    int rb = blockIdx.x >> 3, cs = blockIdx.x & 7;
    int row0 = rb * 64, colb = cs * 1024;
    int wr2 = wave >> 1, wc2 = wave & 1;
    v8s Bfr[2][4];  // one-time reg B-frags (rows of this strip), S-phase
#pragma unroll
    for (int ri = 0; ri < 2; ++ri)
#pragma unroll
        for (int ks = 0; ks < 4; ++ks)
            Bfr[ri][ks] =
                *(const v8s*)(Zb + (size_t)(row0 + wr2 * 32 + ri * 16 + lm) * HD + ks * 32 + lq * 8);
    float rsv[2];
#pragma unroll
    for (int ri = 0; ri < 2; ++ri)
        rsv[ri] = 1.0f / (rowsum[row0 + wr2 * 32 + ri * 16 + lm] + 1e-6f);
    // U accumulators: wave owns h-quarter [wave*32, wave*32+32), all 64 rows
    v4f U[4][2];
#pragma unroll
    for (int rA = 0; rA < 4; ++rA)
#pragma unroll
        for (int hi = 0; hi < 2; ++hi) U[rA][hi] = (v4f){0.f, 0.f, 0.f, 0.f};

    // prologue: stage ZC[0]
#pragma unroll
    for (int t = 0; t < 4; ++t) {
        int idx = tid + t * 256;
        int r = idx >> 4, c8 = (idx & 15) * 8;
        *(uint4*)&ZC[0][r][c8] = *(const uint4*)(Zb + (size_t)(colb + r) * HD + c8);
    }
    __syncthreads();

    int l5 = lane >> 5;         // A-store: row parity
    int c2 = (lane & 31) * 2;   // A-store: col pair

    for (int it = 0; it < 16; ++it) {
        int cur = it & 1;
        int c0 = colb + it * 64;
        uint4 sr[4];
        if (it < 15) {
#pragma unroll
            for (int t = 0; t < 4; ++t) {
                int idx = tid + t * 256;
                int r = idx >> 4, c8 = (idx & 15) * 8;
                sr[t] = *(const uint4*)(Zb + (size_t)(c0 + 64 + r) * HD + c8);
            }
        }
        // U-phase B-operand: wave's own 32-h quarter -> 4 loads, no intra-block duplication
        v8s Bz[2][2];
#pragma unroll
        for (int hi = 0; hi < 2; ++hi)
#pragma unroll
            for (int ks = 0; ks < 2; ++ks)
                Bz[hi][ks] = *(const v8s*)(ZbT + (size_t)(wave * 32 + hi * 16 + lm) * NR + c0 +
                                           ks * 32 + lq * 8);
        // S phase: S^T = (ZC as A) x (Bfr as B); D: r=lm, c=lq*4+reg (unchanged math)
#pragma unroll
        for (int ci = 0; ci < 2; ++ci) {
            v8s Af[4];
#pragma unroll
            for (int ks = 0; ks < 4; ++ks)
                Af[ks] = *(const v8s*)&ZC[cur][wc2 * 32 + ci * 16 + lm][ks * 32 + lq * 8];
            v4f S0 = {0.f, 0.f, 0.f, 0.f}, S1 = {0.f, 0.f, 0.f, 0.f};
#pragma unroll
            for (int ks = 0; ks < 4; ++ks) {
                S0 = __builtin_amdgcn_mfma_f32_16x16x32_bf16(Af[ks], Bfr[0][ks], S0, 0, 0, 0);
                S1 = __builtin_amdgcn_mfma_f32_16x16x32_bf16(Af[ks], Bfr[1][ks], S1, 0, 0, 0);
            }
            int cb = wc2 * 32 + ci * 16 + lq * 4;
            {
                float f0 = fmaxf(S0[0], 0.f) * rsv[0], f1 = fmaxf(S0[1], 0.f) * rsv[0];
                float f2 = fmaxf(S0[2], 0.f) * rsv[0], f3 = fmaxf(S0[3], 0.f) * rsv[0];
                *(uint2*)&PT[cur][wr2 * 32 + lm][cb] = make_uint2(pk2(f0, f1), pk2(f2, f3));
            }
            {
                float f0 = fmaxf(S1[0], 0.f) * rsv[1], f1 = fmaxf(S1[1], 0.f) * rsv[1];
                float f2 = fmaxf(S1[2], 0.f) * rsv[1], f3 = fmaxf(S1[3], 0.f) * rsv[1];
                *(uint2*)&PT[cur][wr2 * 32 + 16 + lm][cb] = make_uint2(pk2(f0, f1), pk2(f2, f3));
            }
        }
        if (it < 15) {
#pragma unroll
            for (int t = 0; t < 4; ++t) {
                int idx = tid + t * 256;
                int r = idx >> 4, c8 = (idx & 15) * 8;
                *(uint4*)&ZC[cur ^ 1][r][c8] = sr[t];
            }
        }
        lds_barrier();  // PT[cur] + ZC[nxt] ready; Bz/nt-stores stay in flight
        // A-stores from PT (PT IS bf16(A)): coalesced — 2 x 256B segments per instr
#pragma unroll
        for (int rr = 0; rr < 8; ++rr) {
            int r = wave * 16 + rr * 2 + l5;
            unsigned pv = *(const unsigned*)&PT[cur][r][c2];
            v2f o;
            o.x = bf2f((ushort)(pv & 0xffffu));
            o.y = bf2f((ushort)(pv >> 16));
            __builtin_nontemporal_store(o, (v2f*)(Ap + (size_t)(row0 + r) * NR + c0 + c2));
        }
        // U phase: U[r][h] += P[r][c] * Z[c][h]; A = PT frags (all 64 rows), B = Bz regs
#pragma unroll
        for (int ks = 0; ks < 2; ++ks) {
            v8s Pf[4];
#pragma unroll
            for (int rA = 0; rA < 4; ++rA)
                Pf[rA] = *(const v8s*)&PT[cur][rA * 16 + lm][ks * 32 + lq * 8];
#pragma unroll
            for (int hi = 0; hi < 2; ++hi)
#pragma unroll
                for (int rA = 0; rA < 4; ++rA)
                    U[rA][hi] = __builtin_amdgcn_mfma_f32_16x16x32_bf16(Pf[rA], Bz[hi][ks], U[rA][hi], 0, 0, 0);
        }
    }
    // epilogue: D layout -> r = row0 + rA*16 + lq*4 + j, h = wave*32 + hi*16 + lm
#pragma unroll
    for (int rA = 0; rA < 4; ++rA)
#pragma unroll
        for (int hi = 0; hi < 2; ++hi)
#pragma unroll
            for (int j = 0; j < 4; ++j)
                atomicAdd(&outp[(size_t)(row0 + rA * 16 + lq * 4 + j) * HD +
                                wave * 32 + hi * 16 + lm],
                          U[rA][hi][j]);
}

extern "C" void kernel_launch(void* const* d_in, const int* in_sizes, int n_in,
                              void* d_out, int out_size, void* d_ws, size_t ws_size,
                              hipStream_t stream) {
    (void)in_sizes; (void)n_in; (void)out_size; (void)ws_size;
    const float* X = (const float*)d_in[0];
    const float* W = (const float*)d_in[1];
    float* outp = (float*)d_out;
    float* Ap = outp + (size_t)NR * HD;  // A follows out in d_out
    char* ws = (char*)d_ws;
    ushort* Zb = (ushort*)ws;                                 // 2 MB
    ushort* ZbT = (ushort*)(ws + (size_t)NR * HD * 2);        // 2 MB
    float* rowsum = (float*)(ws + (size_t)NR * HD * 4);       // 32 KB  (ws total 8.03MB, proven)

    (void)hipMemsetAsync(outp, 0, (size_t)NR * HD * sizeof(float), stream);
    (void)hipMemsetAsync(rowsum, 0, NR * sizeof(float), stream);
    k_z<<<dim3(NR / 16), dim3(256), 0, stream>>>(X, W, Zb, ZbT);
    k_rowsum<<<dim3(1024), dim3(256), 0, stream>>>(Zb, rowsum);
    k_main<<<dim3(1024), dim3(256), 0, stream>>>(Zb, ZbT, rowsum, outp, Ap);
}